// Round 3
// baseline (27273.285 us; speedup 1.0000x reference)
//
#include <hip/hip_runtime.h>

// Problem dims
#define Lz   128
#define Hd   1024
#define Od   64
#define Sq   256
#define Bt   512
#define K1   1216   // h1(1024) | z(128) | out(64)  -- fold un-materialized (rank-64)
#define K2q  2048   // h1n(1024) | h2(1024)
#define G4H  4096
#define NBLK 512u   // 16 mb x 32 bn2 (32x128 tiles), 2 blocks/CU; out folded into 32

typedef __attribute__((ext_vector_type(8))) short  short8;
typedef __attribute__((ext_vector_type(4))) float  floatx4;

__device__ __forceinline__ short f2bf(float x) {
  unsigned u = __float_as_uint(x);
  unsigned r = (u + 0x7fffu + ((u >> 16) & 1u)) >> 16;
  return (short)r;
}
__device__ __forceinline__ float sigf(float x)   { return 1.0f / (1.0f + __expf(-x)); }
__device__ __forceinline__ float tanhf_(float x) { return 1.0f - 2.0f / (__expf(2.0f * x) + 1.0f); }

// cached load (L2-resident; for static data: weights, z)
__device__ __forceinline__ void gl_lds_w(const short* g, void* l) {
  __builtin_amdgcn_global_load_lds(
      (__attribute__((address_space(1))) const void*)g,
      (__attribute__((address_space(3))) void*)l, 16, 0, 0);
}
// coherent dynamic-activation load: sc0|nt|sc1 -> force L2 miss (never stale),
// no L2 allocation (never evicts weights), reads MALL (sees write-through stores)
__device__ __forceinline__ void gl_lds_a(const short* g, void* l) {
  __builtin_amdgcn_global_load_lds(
      (__attribute__((address_space(1))) const void*)g,
      (__attribute__((address_space(3))) void*)l, 16, 0, 19);
}
// write-through coherent h-state store (visible at MALL to all XCDs)
__device__ __forceinline__ void st_wt(short* p, short v) {
  asm volatile("global_store_short %0, %1, off sc0 sc1"
               :: "v"(p), "v"((unsigned)(unsigned short)v) : "memory");
}

#define S_BARRIER() asm volatile("s_barrier" ::: "memory")
#define WAITVM(n)   asm volatile("s_waitcnt vmcnt(" #n ")" ::: "memory")

// ---- fence-free grid barrier: relaxed agent atomics only (visibility proven R4/R5).
__device__ __forceinline__ void gbar(unsigned* cnt, unsigned* gen) {
  __syncthreads();
  if (threadIdx.x == 0) {
    unsigned g = __hip_atomic_load(gen, __ATOMIC_RELAXED, __HIP_MEMORY_SCOPE_AGENT);
    unsigned a = __hip_atomic_fetch_add(cnt, 1u, __ATOMIC_RELAXED, __HIP_MEMORY_SCOPE_AGENT);
    if (a == NBLK - 1u) {
      __hip_atomic_store(cnt, 0u, __ATOMIC_RELAXED, __HIP_MEMORY_SCOPE_AGENT);
      __hip_atomic_store(gen, g + 1u, __ATOMIC_RELAXED, __HIP_MEMORY_SCOPE_AGENT);
    } else {
      while (__hip_atomic_load(gen, __ATOMIC_RELAXED, __HIP_MEMORY_SCOPE_AGENT) == g)
        __builtin_amdgcn_s_sleep(8);
    }
  }
  __syncthreads();
}

// ---- weight row reorder: group bn (0..63) holds 64 rows: gate g (ifgo), j (0..15)
__device__ __forceinline__ int oldrow(int nr) {
  int bn = nr >> 6, rem = nr & 63, g = rem >> 4, jj = rem & 15;
  return g * Hd + bn * 16 + jj;
}

struct Params {
  const short *W1r, *W2r, *Woutb;
  const float *b0v, *b1v, *bout;
  short *A1_0, *A1_1, *A2_0, *A2_1;
  float *c1, *c2, *out;
  unsigned *bcnt, *bgen;
  int *outcnt;
};

// ================= prep kernels =================
__global__ void k_conv_w1a(const float* __restrict__ Whh0, short* __restrict__ W1r) {
  int idx = blockIdx.x * 256 + threadIdx.x;        // 4096*1024
  int nr = idx >> 10, k = idx & 1023;
  W1r[nr * K1 + k] = f2bf(Whh0[oldrow(nr) * Hd + k]);
}
__global__ void k_conv_w1c(const float* __restrict__ Wih0, short* __restrict__ W1r) {
  int idx = blockIdx.x * 256 + threadIdx.x;        // 4096*128 (z cols)
  int nr = idx >> 7, kz = idx & 127;
  W1r[nr * K1 + 1024 + kz] = f2bf(Wih0[oldrow(nr) * (Lz + Od) + kz]);
}
__global__ void k_conv_w1d(const float* __restrict__ Wih0, short* __restrict__ W1r) {
  int idx = blockIdx.x * 256 + threadIdx.x;        // 4096*64 (out-feedback cols)
  int nr = idx >> 6, j = idx & 63;
  W1r[nr * K1 + 1152 + j] = f2bf(Wih0[oldrow(nr) * (Lz + Od) + Lz + j]);
}
__global__ void k_conv_w2(const float* __restrict__ Wih1, const float* __restrict__ Whh1,
                          short* __restrict__ W2r) {
  int idx = blockIdx.x * 256 + threadIdx.x;        // 4096*2048
  int nr = idx >> 11, k = idx & 2047;
  int orow = oldrow(nr);
  float v = (k < Hd) ? Wih1[orow * Hd + k] : Whh1[orow * Hd + (k - Hd)];
  W2r[nr * K2q + k] = f2bf(v);
}
__global__ void k_conv_wout(const float* __restrict__ Wout, short* __restrict__ Woutb) {
  int idx = blockIdx.x * 256 + threadIdx.x;        // 64*1024
  Woutb[idx] = f2bf(Wout[idx]);
}
__global__ void k_vec(const float* __restrict__ bih0, const float* __restrict__ bhh0,
                      const float* __restrict__ bih1, const float* __restrict__ bhh1,
                      float* __restrict__ b0v, float* __restrict__ b1v,
                      int* __restrict__ barzero) {
  int n = blockIdx.x * 256 + threadIdx.x;          // 4096 (original gate order)
  if (n < 64) barzero[n] = 0;                      // zero barrier/counter state
  b0v[n] = bih0[n] + bhh0[n];
  b1v[n] = bih1[n] + bhh1[n];
}
__global__ void k_init(const float* __restrict__ z, const float* __restrict__ Wh,
                       const float* __restrict__ bh, const float* __restrict__ Wc,
                       const float* __restrict__ bc,
                       short* __restrict__ A1_0, short* __restrict__ A2_0,
                       float* __restrict__ c1, float* __restrict__ c2) {
  int idx = blockIdx.x * 256 + threadIdx.x;        // 512*1024
  int m = idx >> 10, n = idx & 1023;
  const float* zr = z + m * Lz;
  const float* whr = Wh + n * Lz;
  const float* wcr = Wc + n * Lz;
  float hh = bh[n], cc = bc[n];
  #pragma unroll 8
  for (int k = 0; k < Lz; ++k) { float zv = zr[k]; hh += zv * whr[k]; cc += zv * wcr[k]; }
  c1[idx] = cc;
  c2[idx] = cc;
  short hb = f2bf(hh);
  A1_0[m * K1 + n] = hb;                 // h1(-1) = h0
  if (n < Od) A1_0[m * K1 + 1152 + n] = 0;   // out(-1) = 0
  A2_0[m * K2q + Hd + n] = hb;           // h2(-1) = h0
}
__global__ void k_initz(const float* __restrict__ z, short* __restrict__ A1_0,
                        short* __restrict__ A1_1) {
  int idx = blockIdx.x * 256 + threadIdx.x;        // 512*128
  int m = idx >> 7, k = idx & 127;
  short v = f2bf(z[idx]);
  A1_0[m * K1 + 1024 + k] = v;
  A1_1[m * K1 + 1024 + k] = v;
}

// ================= main persistent kernel =================
#define MFMA16(a, b, c) __builtin_amdgcn_mfma_f32_16x16x32_bf16(a, b, c, 0, 0, 0)
#define BUFSH 10240   // shorts per ring buffer: A 32x64 (2048) + W 128x64 (8192)
#define NBUF  3       // prefetch depth 2 (R0-proven sync structure)
#define LDS_BYTES (NBUF * BUFSH * 2)   // 60 KB -> 2 blocks/CU

// one K-chunk (64 cols) of the 32x128 tile into ring buffer b. XOR-swizzled
// (R3-proven): LDS chunk-slot sl of row r holds global chunk sl^(r&7).
__device__ __forceinline__ void stage_chunk(const short* __restrict__ Ab, int astride,
                                            const short* __restrict__ Wb,
                                            int kk, int zstart, short* sm, int b, int tid) {
  const int kb = kk * 64;
  short* as = sm + b * BUFSH;
  short* ws = as + 2048;
  const bool stat = (kk == zstart) || (kk == zstart + 1);   // static z cols: cached
  {
    int s = tid;                          // A: 32 rows x 8 chunks of 8 shorts
    int row = s >> 3, cg = (s & 7) ^ (row & 7);
    const short* gp = Ab + (size_t)row * astride + kb + cg * 8;
    if (stat) gl_lds_w(gp, as + s * 8);
    else      gl_lds_a(gp, as + s * 8);
  }
  #pragma unroll
  for (int i = 0; i < 4; ++i) {           // W: 128 rows x 8 chunks
    int s = i * 256 + tid;
    int row = s >> 3, cg = (s & 7) ^ (row & 7);
    gl_lds_w(Wb + (size_t)row * astride + kb + cg * 8, ws + s * 8);
  }
}

// ---- folded out-projection, register-based (no LDS): 32 designated blocks,
// 16 batch rows each. A-frag (h2 rows) loaded straight from MALL via nt loads;
// B-frag (Woutb) via plain loads; exact-count vmcnt pipelining, 2 groups deep.
// Runs BEFORE the window-A prologue; its stores retire under the ring's first
// WAITVM(10), where outcnt is bumped (no drain on the critical path).
__device__ __forceinline__ void out_reg(const short* __restrict__ h2src,
    const short* __restrict__ Wo, const float* __restrict__ boutv,
    float* __restrict__ outp, int tt, int mo,
    short* __restrict__ ofb, int tid)
{
  const int lane = tid & 63, w = tid >> 6;
  const int l15 = lane & 15, q = lane >> 4;
  const short* ap = h2src + (size_t)(mo + l15) * K2q + Hd + q * 8;
  const short* bp = Wo + (size_t)(w * 16 + l15) * Hd + q * 8;
  floatx4 acc = {};
  short8 A0, B0, A1, B1, A2, B2, A3, B3;
#define OLA(r, kk) asm volatile("global_load_dwordx4 %0, %1, off sc0 sc1 nt" \
    : "=v"(r) : "v"(ap + (kk) * 32) : "memory")
#define OLB(r, kk) asm volatile("global_load_dwordx4 %0, %1, off" \
    : "=v"(r) : "v"(bp + (kk) * 32) : "memory")
  OLA(A0, 0); OLB(B0, 0); OLA(A1, 1); OLB(B1, 1);     // group 0 (kk 0,1)
  OLA(A2, 2); OLB(B2, 2); OLA(A3, 3); OLB(B3, 3);     // group 1 (kk 2,3)
  #pragma unroll
  for (int g = 0; g < 16; g += 2) {
    WAITVM(4); __builtin_amdgcn_sched_barrier(0);      // group g retired
    acc = MFMA16(A0, B0, acc); acc = MFMA16(A1, B1, acc);
    if (g + 2 < 16) { OLA(A0, 2*(g+2)); OLB(B0, 2*(g+2));
                      OLA(A1, 2*(g+2)+1); OLB(B1, 2*(g+2)+1); }
    if (g + 3 < 16) { WAITVM(4); } else { WAITVM(0); } // group g+1 retired
    __builtin_amdgcn_sched_barrier(0);
    acc = MFMA16(A2, B2, acc); acc = MFMA16(A3, B3, acc);
    if (g + 3 < 16) { OLA(A2, 2*(g+3)); OLB(B2, 2*(g+3));
                      OLA(A3, 2*(g+3)+1); OLB(B3, 2*(g+3)+1); }
  }
#undef OLA
#undef OLB
  #pragma unroll
  for (int r = 0; r < 4; ++r) {
    int m = mo + q * 4 + r;
    int n = w * 16 + l15;
    float v = acc[r] + boutv[n];
    outp[(size_t)m * (Sq * Od) + (size_t)tt * Od + n] = v;
    if (ofb) st_wt(ofb + (size_t)m * K1 + 1152 + n, f2bf(v));
  }
}

// 32x128 tile, 4 waves: w = (mh<<1)|gh; mh = 16-row half, gh = 64-col group
// (16 h-cols x 4 gates). Ring NBUF=3 depth 2, two barriers/chunk (R0-proven).
// bump: outcnt incremented at kk==0 after WAITVM(10) (out stores provably
// retired: 8 stores + 15 ring loads issued, <=10 left => stores done).
__device__ __forceinline__ void gemm_win(
    const short* __restrict__ Asrc, int astride, int nk, int zstart,
    const short* __restrict__ Wsrc,
    const float* __restrict__ bz, float cr[4],
    short* __restrict__ hd0, int hs0, int ho0,
    short* __restrict__ hd1, int hs1, int ho1,
    int m0, int bn2, short* sm, int tid,
    int* __restrict__ ocnt, int othresh, int* __restrict__ bump)
{
  const int lane = tid & 63, w = tid >> 6;
  const int l15 = lane & 15, q = lane >> 4;
  const int mh = w >> 1, gh = w & 1;
  floatx4 acc[4] = {};

  const short* Ab = Asrc + (size_t)m0 * astride;
  const short* Wb = Wsrc + (size_t)(bn2 * 128) * astride;

  stage_chunk(Ab, astride, Wb, 0, zstart, sm, 0, tid);
  stage_chunk(Ab, astride, Wb, 1, zstart, sm, 1, tid);
  for (int kk = 0; kk < nk; ++kk) {
    S_BARRIER();
    if (kk + 2 < nk) {
      if (ocnt && kk + 2 == nk - 1) {     // out-feedback chunk: wait for out-jobs
        while (__hip_atomic_load(ocnt, __ATOMIC_RELAXED, __HIP_MEMORY_SCOPE_AGENT) < othresh)
          __builtin_amdgcn_s_sleep(1);
      }
      stage_chunk(Ab, astride, Wb, kk + 2, zstart, sm, (kk + 2) % NBUF, tid);
      WAITVM(10);
    }
    else if (kk + 1 < nk) { WAITVM(5); }
    else { WAITVM(0); }
    S_BARRIER();
    if (bump && kk == 0 && tid == 0)
      __hip_atomic_fetch_add(bump, 1, __ATOMIC_RELAXED, __HIP_MEMORY_SCOPE_AGENT);
    const short* as = sm + (kk % NBUF) * BUFSH;
    const short* ws = as + 2048;
    #pragma unroll
    for (int ks = 0; ks < 2; ++ks) {
      const int cc = ks * 4 + q;
      const int ra = mh * 16 + l15;
      short8 a = *(const short8*)(as + (ra * 8 + (cc ^ (ra & 7))) * 8);
      #pragma unroll
      for (int g = 0; g < 4; ++g) {
        const int rw = gh * 64 + g * 16 + l15;
        short8 b = *(const short8*)(ws + (rw * 8 + (cc ^ (rw & 7))) * 8);
        acc[g] = MFMA16(a, b, acc[g]);
      }
    }
  }
  // fused LSTM cell epilogue; h written through to MALL (cross-XCD coherent)
  const int colh = bn2 * 32 + gh * 16 + l15;
  #pragma unroll
  for (int r = 0; r < 4; ++r) {
    const int mg = m0 + mh * 16 + q * 4 + r;
    float iv = acc[0][r] + bz[0];
    float fv = acc[1][r] + bz[1];
    float gv = acc[2][r] + bz[2];
    float ov = acc[3][r] + bz[3];
    float cn = sigf(fv) * cr[r] + sigf(iv) * tanhf_(gv);
    cr[r] = cn;
    short hb = f2bf(sigf(ov) * tanhf_(cn));
    st_wt(hd0 + (size_t)mg * hs0 + ho0 + colh, hb);
    if (hd1) st_wt(hd1 + (size_t)mg * hs1 + ho1 + colh, hb);
  }
}

__global__ __launch_bounds__(256, 2) void lstm_main(Params p) {
  extern __shared__ __align__(16) short smem[];   // 3 x 20 KB = 60 KB
  const int tid = threadIdx.x;
  const int blk = blockIdx.x;
  const int xcd = blk & 7, j = blk >> 3;          // 64 blocks per XCD
  const int bn2 = xcd * 4 + (j & 3);              // 0..31 (4 N-slices per XCD L2)
  const int m0 = (j >> 2) * 32;                   // mb 0..15
  const bool ojob = ((j & 15) == 0);              // j in {0,16,32,48}: 32 jobs
  const int mo = (xcd * 4 + (j >> 4)) * 16;       // out-job batch rows (16 each)
  const int lane = tid & 63, w = tid >> 6;
  const int l15 = lane & 15, q = lane >> 4;
  const int mh = w >> 1, gh = w & 1;
  const int colh = bn2 * 32 + gh * 16 + l15;

  float bA[4], bB[4], c1r[4], c2r[4];
  #pragma unroll
  for (int g = 0; g < 4; ++g) {
    bA[g] = p.b0v[g * Hd + colh];
    bB[g] = p.b1v[g * Hd + colh];
  }
  #pragma unroll
  for (int r = 0; r < 4; ++r) {
    const int mg = m0 + mh * 16 + q * 4 + r;
    c1r[r] = p.c1[mg * Hd + colh];
    c2r[r] = p.c2[mg * Hd + colh];
  }

  for (int t = 0; t < Sq; ++t) {
    const int par = t & 1;
    const short* A1p = par ? p.A1_1 : p.A1_0;
    short* A1n = par ? p.A1_0 : p.A1_1;
    short* A2p = par ? p.A2_1 : p.A2_0;
    short* A2n = par ? p.A2_0 : p.A2_1;
    // out(t-1) on designated blocks: register-based, before the ring prologue;
    // all its loads retire via internal exact-count waits, stores retire under
    // the ring's first WAITVM(10) where outcnt is bumped.
    if (ojob && t > 0)
      out_reg(A2p, p.Woutb, p.bout, p.out, t - 1, mo, (short*)A1p, tid);
    // window A: layer-0 gates; A1 = [h1 | z | out(t-1)], out-chunk flag-guarded
    gemm_win(A1p, K1, 19, 16, p.W1r, bA, c1r,
             A1n, K1, 0, (short*)A2p, K2q, 0, m0, bn2, smem, tid,
             p.outcnt, 32 * t, (ojob && t > 0) ? p.outcnt : nullptr);
    gbar(p.bcnt, p.bgen);
    // window B: layer-1 gates; h2n only into A2n
    gemm_win(A2p, K2q, 32, -2, p.W2r, bB, c2r,
             A2n, K2q, Hd, (short*)nullptr, 0, 0, m0, bn2, smem, tid,
             nullptr, 0, nullptr);
    gbar(p.bcnt, p.bgen);
  }
  // final: out(255) from h2(255) in A2_0 (phase B of t=255 wrote A2n = A2_0)
  if (ojob)
    out_reg(p.A2_0, p.Woutb, p.bout, p.out, Sq - 1, mo, (short*)nullptr, tid);
}

// ================= host =================
extern "C" void kernel_launch(void* const* d_in, const int* in_sizes, int n_in,
                              void* d_out, int out_size, void* d_ws, size_t ws_size,
                              hipStream_t stream) {
  const float* z    = (const float*)d_in[0];
  const float* Wh   = (const float*)d_in[1];
  const float* bh   = (const float*)d_in[2];
  const float* Wc   = (const float*)d_in[3];
  const float* bc   = (const float*)d_in[4];
  const float* Wih0 = (const float*)d_in[5];
  const float* Whh0 = (const float*)d_in[6];
  const float* bih0 = (const float*)d_in[7];
  const float* bhh0 = (const float*)d_in[8];
  const float* Wih1 = (const float*)d_in[9];
  const float* Whh1 = (const float*)d_in[10];
  const float* bih1 = (const float*)d_in[11];
  const float* bhh1 = (const float*)d_in[12];
  const float* Wout = (const float*)d_in[13];
  const float* bout = (const float*)d_in[14];
  float* out = (float*)d_out;

  char* ws = (char*)d_ws;
  size_t off = 0;
  auto carve = [&](size_t bytes) { char* p = ws + off; off = (off + bytes + 255) & ~size_t(255); return p; };
  short* W1r   = (short*)carve((size_t)G4H * K1 * 2);
  short* W2r   = (short*)carve((size_t)G4H * K2q * 2);
  short* Woutb = (short*)carve((size_t)Od * Hd * 2);
  float* b0v   = (float*)carve(G4H * 4);
  float* b1v   = (float*)carve(G4H * 4);
  short* A1_0  = (short*)carve((size_t)Bt * K1 * 2);
  short* A1_1  = (short*)carve((size_t)Bt * K1 * 2);
  short* A2_0  = (short*)carve((size_t)Bt * K2q * 2);
  short* A2_1  = (short*)carve((size_t)Bt * K2q * 2);
  float* c1    = (float*)carve((size_t)Bt * Hd * 4);
  float* c2    = (float*)carve((size_t)Bt * Hd * 4);
  int*   barr  = (int*)carve(256);   // [0]=cnt [1]=gen [2]=outcnt

  k_conv_w1a<<<16384, 256, 0, stream>>>(Whh0, W1r);
  k_conv_w1c<<<2048, 256, 0, stream>>>(Wih0, W1r);
  k_conv_w1d<<<1024, 256, 0, stream>>>(Wih0, W1r);
  k_conv_w2 <<<32768, 256, 0, stream>>>(Wih1, Whh1, W2r);
  k_conv_wout<<<256, 256, 0, stream>>>(Wout, Woutb);
  k_vec<<<16, 256, 0, stream>>>(bih0, bhh0, bih1, bhh1, b0v, b1v, barr);
  k_init<<<2048, 256, 0, stream>>>(z, Wh, bh, Wc, bc, A1_0, A2_0, c1, c2);
  k_initz<<<256, 256, 0, stream>>>(z, A1_0, A1_1);

  Params pr{W1r, W2r, Woutb, b0v, b1v, bout,
            A1_0, A1_1, A2_0, A2_1, c1, c2, out,
            (unsigned*)barr, (unsigned*)(barr + 1), barr + 2};

  (void)hipFuncSetAttribute((const void*)lstm_main,
                            hipFuncAttributeMaxDynamicSharedMemorySize, LDS_BYTES);
  lstm_main<<<dim3(NBLK), dim3(256), LDS_BYTES, stream>>>(pr);
}

// Round 4
// 13922.964 us; speedup vs baseline: 1.9589x; 1.9589x over previous
//
#include <hip/hip_runtime.h>

// Problem dims
#define Lz   128
#define Hd   1024
#define Od   64
#define Sq   256
#define Bt   512
#define K1   1216   // h1(1024) | z(128) | out(64)  -- fold un-materialized (rank-64)
#define K2q  2048   // h1n(1024) | h2(1024)
#define G4H  4096
#define NBLK 144u   // 128 GEMM (8 mb x 16 bn, 64x256 tiles, 512 thr) + 16 out

typedef __attribute__((ext_vector_type(8))) short  short8;
typedef __attribute__((ext_vector_type(4))) float  floatx4;

__device__ __forceinline__ short f2bf(float x) {
  unsigned u = __float_as_uint(x);
  unsigned r = (u + 0x7fffu + ((u >> 16) & 1u)) >> 16;
  return (short)r;
}
__device__ __forceinline__ float sigf(float x)   { return 1.0f / (1.0f + __expf(-x)); }
__device__ __forceinline__ float tanhf_(float x) { return 1.0f - 2.0f / (__expf(2.0f * x) + 1.0f); }

// cached load (L2-resident; for static data: weights, z)
__device__ __forceinline__ void gl_lds_w(const short* g, void* l) {
  __builtin_amdgcn_global_load_lds(
      (__attribute__((address_space(1))) const void*)g,
      (__attribute__((address_space(3))) void*)l, 16, 0, 0);
}
// coherent dynamic-activation load: sc0|nt|sc1 -> force L2 miss (never stale),
// no L2 allocation (never evicts weights), reads MALL (sees write-through stores)
__device__ __forceinline__ void gl_lds_a(const short* g, void* l) {
  __builtin_amdgcn_global_load_lds(
      (__attribute__((address_space(1))) const void*)g,
      (__attribute__((address_space(3))) void*)l, 16, 0, 19);
}
// write-through coherent h-state store (visible at MALL to all XCDs)
__device__ __forceinline__ void st_wt(short* p, short v) {
  asm volatile("global_store_short %0, %1, off sc0 sc1"
               :: "v"(p), "v"((unsigned)(unsigned short)v) : "memory");
}

#define S_BARRIER() asm volatile("s_barrier" ::: "memory")
#define WAITVM(n)   asm volatile("s_waitcnt vmcnt(" #n ")" ::: "memory")

// ---- fence-free grid barrier: relaxed agent atomics only (visibility proven R4/R5).
__device__ __forceinline__ void gbar(unsigned* cnt, unsigned* gen) {
  __syncthreads();
  if (threadIdx.x == 0) {
    unsigned g = __hip_atomic_load(gen, __ATOMIC_RELAXED, __HIP_MEMORY_SCOPE_AGENT);
    unsigned a = __hip_atomic_fetch_add(cnt, 1u, __ATOMIC_RELAXED, __HIP_MEMORY_SCOPE_AGENT);
    if (a == NBLK - 1u) {
      __hip_atomic_store(cnt, 0u, __ATOMIC_RELAXED, __HIP_MEMORY_SCOPE_AGENT);
      __hip_atomic_store(gen, g + 1u, __ATOMIC_RELAXED, __HIP_MEMORY_SCOPE_AGENT);
    } else {
      while (__hip_atomic_load(gen, __ATOMIC_RELAXED, __HIP_MEMORY_SCOPE_AGENT) == g)
        __builtin_amdgcn_s_sleep(8);
    }
  }
  __syncthreads();
}

// ---- weight row reorder: group bn (0..63) holds 64 rows: gate g (ifgo), j (0..15)
__device__ __forceinline__ int oldrow(int nr) {
  int bn = nr >> 6, rem = nr & 63, g = rem >> 4, jj = rem & 15;
  return g * Hd + bn * 16 + jj;
}

struct Params {
  const short *W1r, *W2r, *Woutb;
  const float *b0v, *b1v, *bout;
  short *A1_0, *A1_1, *A2_0, *A2_1;
  float *c1, *c2, *out;
  unsigned *bcnt, *bgen;
  int *outcnt;
};

// ================= prep kernels =================
__global__ void k_conv_w1a(const float* __restrict__ Whh0, short* __restrict__ W1r) {
  int idx = blockIdx.x * 256 + threadIdx.x;        // 4096*1024
  int nr = idx >> 10, k = idx & 1023;
  W1r[nr * K1 + k] = f2bf(Whh0[oldrow(nr) * Hd + k]);
}
__global__ void k_conv_w1c(const float* __restrict__ Wih0, short* __restrict__ W1r) {
  int idx = blockIdx.x * 256 + threadIdx.x;        // 4096*128 (z cols)
  int nr = idx >> 7, kz = idx & 127;
  W1r[nr * K1 + 1024 + kz] = f2bf(Wih0[oldrow(nr) * (Lz + Od) + kz]);
}
__global__ void k_conv_w1d(const float* __restrict__ Wih0, short* __restrict__ W1r) {
  int idx = blockIdx.x * 256 + threadIdx.x;        // 4096*64 (out-feedback cols)
  int nr = idx >> 6, j = idx & 63;
  W1r[nr * K1 + 1152 + j] = f2bf(Wih0[oldrow(nr) * (Lz + Od) + Lz + j]);
}
__global__ void k_conv_w2(const float* __restrict__ Wih1, const float* __restrict__ Whh1,
                          short* __restrict__ W2r) {
  int idx = blockIdx.x * 256 + threadIdx.x;        // 4096*2048
  int nr = idx >> 11, k = idx & 2047;
  int orow = oldrow(nr);
  float v = (k < Hd) ? Wih1[orow * Hd + k] : Whh1[orow * Hd + (k - Hd)];
  W2r[nr * K2q + k] = f2bf(v);
}
__global__ void k_conv_wout(const float* __restrict__ Wout, short* __restrict__ Woutb) {
  int idx = blockIdx.x * 256 + threadIdx.x;        // 64*1024
  Woutb[idx] = f2bf(Wout[idx]);
}
__global__ void k_vec(const float* __restrict__ bih0, const float* __restrict__ bhh0,
                      const float* __restrict__ bih1, const float* __restrict__ bhh1,
                      float* __restrict__ b0v, float* __restrict__ b1v,
                      int* __restrict__ barzero) {
  int n = blockIdx.x * 256 + threadIdx.x;          // 4096 (original gate order)
  if (n < 64) barzero[n] = 0;                      // zero barrier/counter state
  b0v[n] = bih0[n] + bhh0[n];
  b1v[n] = bih1[n] + bhh1[n];
}
__global__ void k_init(const float* __restrict__ z, const float* __restrict__ Wh,
                       const float* __restrict__ bh, const float* __restrict__ Wc,
                       const float* __restrict__ bc,
                       short* __restrict__ A1_0, short* __restrict__ A2_0,
                       float* __restrict__ c1, float* __restrict__ c2) {
  int idx = blockIdx.x * 256 + threadIdx.x;        // 512*1024
  int m = idx >> 10, n = idx & 1023;
  const float* zr = z + m * Lz;
  const float* whr = Wh + n * Lz;
  const float* wcr = Wc + n * Lz;
  float hh = bh[n], cc = bc[n];
  #pragma unroll 8
  for (int k = 0; k < Lz; ++k) { float zv = zr[k]; hh += zv * whr[k]; cc += zv * wcr[k]; }
  c1[idx] = cc;
  c2[idx] = cc;
  short hb = f2bf(hh);
  A1_0[m * K1 + n] = hb;                 // h1(-1) = h0
  if (n < Od) A1_0[m * K1 + 1152 + n] = 0;   // out(-1) = 0
  A2_0[m * K2q + Hd + n] = hb;           // h2(-1) = h0
}
__global__ void k_initz(const float* __restrict__ z, short* __restrict__ A1_0,
                        short* __restrict__ A1_1) {
  int idx = blockIdx.x * 256 + threadIdx.x;        // 512*128
  int m = idx >> 7, k = idx & 127;
  short v = f2bf(z[idx]);
  A1_0[m * K1 + 1024 + k] = v;
  A1_1[m * K1 + 1024 + k] = v;
}

// ================= main persistent kernel =================
#define MFMA16(a, b, c) __builtin_amdgcn_mfma_f32_16x16x32_bf16(a, b, c, 0, 0, 0)
#define BUFSH 20480   // shorts per LDS buffer: A 64x64 (4096) + W 256x64 (16384)
#define NBUF  3       // prefetch depth 2 (R0-proven sync structure)
#define LDS_BYTES (NBUF * BUFSH * 2)   // 120 KB -> 1 block/CU

// 64x256 tile, 8 waves (= two R0 blocks merged: halves coherent-A redundancy).
// wave w: mh = w>>2 (32-row half), gq = w&3 (64-gate-row group of the 256).
// XOR-swizzled LDS (R3-proven): chunk-slot sl of row r holds global chunk sl^(r&7).
__device__ __forceinline__ void gemm_win(
    const short* __restrict__ Asrc, int astride, int nk, int zstart,
    const short* __restrict__ Wsrc,
    const float* __restrict__ bz, float cr[2][4],
    short* __restrict__ hd0, int hs0, int ho0,
    short* __restrict__ hd1, int hs1, int ho1,
    int m0, int bn, short* sm, int tid,
    int* __restrict__ ocnt, int othresh)
{
  const int lane = tid & 63, w = tid >> 6;
  const int l15 = lane & 15, q = lane >> 4;
  const int mh = w >> 2, gq = w & 3;
  floatx4 acc[2][4] = {};

  const short* Ab = Asrc + (size_t)m0 * astride;
  const short* Wb = Wsrc + (size_t)(bn * 256) * astride;

  auto stage = [&](int kk, int b) {
    const int kb = kk * 64;
    short* as = sm + b * BUFSH;
    short* ws = as + 4096;
    const bool stat = (kk == zstart) || (kk == zstart + 1);   // static z cols: cached
    {
      int s = tid;                          // A: 64 rows x 8 chunks (512 thr, 1 ea)
      int row = s >> 3, cg = (s & 7) ^ (row & 7);
      const short* gp = Ab + (size_t)row * astride + kb + cg * 8;
      if (stat) gl_lds_w(gp, as + s * 8);
      else      gl_lds_a(gp, as + s * 8);
    }
    #pragma unroll
    for (int i = 0; i < 4; ++i) {           // W: 256 rows x 8 chunks
      int s = i * 512 + tid;
      int row = s >> 3, cg = (s & 7) ^ (row & 7);
      gl_lds_w(Wb + (size_t)row * astride + kb + cg * 8, ws + s * 8);
    }
  };

  stage(0, 0);
  stage(1, 1);
  for (int kk = 0; kk < nk; ++kk) {
    S_BARRIER();
    if (kk + 2 < nk) {
      if (ocnt && kk + 2 == nk - 1) {     // out-feedback chunk: wait for out-blocks
        while (__hip_atomic_load(ocnt, __ATOMIC_RELAXED, __HIP_MEMORY_SCOPE_AGENT) < othresh)
          __builtin_amdgcn_s_sleep(1);
      }
      stage(kk + 2, (kk + 2) % NBUF);
      WAITVM(10);
    }
    else if (kk + 1 < nk) { WAITVM(5); }
    else { WAITVM(0); }
    S_BARRIER();
    const short* as = sm + (kk % NBUF) * BUFSH;
    const short* ws = as + 4096;
    #pragma unroll
    for (int ks = 0; ks < 2; ++ks) {
      const int cc = ks * 4 + q;
      short8 a[2];
      #pragma unroll
      for (int mt = 0; mt < 2; ++mt) {
        const int ra = mh * 32 + mt * 16 + l15;
        a[mt] = *(const short8*)(as + (ra * 8 + (cc ^ (ra & 7))) * 8);
      }
      #pragma unroll
      for (int g = 0; g < 4; ++g) {
        const int rw = gq * 64 + g * 16 + l15;
        short8 b = *(const short8*)(ws + (rw * 8 + (cc ^ (rw & 7))) * 8);
        acc[0][g] = MFMA16(a[0], b, acc[0][g]);
        acc[1][g] = MFMA16(a[1], b, acc[1][g]);
      }
    }
  }
  // fused LSTM cell epilogue; h written through to MALL (cross-XCD coherent)
  const int colh = bn * 64 + gq * 16 + l15;
  #pragma unroll
  for (int mt = 0; mt < 2; ++mt) {
    #pragma unroll
    for (int r = 0; r < 4; ++r) {
      const int mg = m0 + mh * 32 + mt * 16 + q * 4 + r;
      float iv = acc[mt][0][r] + bz[0];
      float fv = acc[mt][1][r] + bz[1];
      float gv = acc[mt][2][r] + bz[2];
      float ov = acc[mt][3][r] + bz[3];
      float cn = sigf(fv) * cr[mt][r] + sigf(iv) * tanhf_(gv);
      cr[mt][r] = cn;
      short hb = f2bf(sigf(ov) * tanhf_(cn));
      st_wt(hd0 + (size_t)mg * hs0 + ho0 + colh, hb);
      if (hd1) st_wt(hd1 + (size_t)mg * hs1 + ho1 + colh, hb);
    }
  }
}

// out-blocks (512 thr): out(tt) = h2(tt)@Wout.T + bout; h2 from A2 h2-slot;
// publish bf16 into A1's out-segment + bump completion counter.
__device__ __forceinline__ void out_win(const short* __restrict__ h2src,
    short* __restrict__ a1dst,
    const short* __restrict__ Wo, const float* __restrict__ bout,
    float* __restrict__ out, int tt, int ob, short* sm, int tid,
    int* __restrict__ ocnt)
{
  const int lane = tid & 63, w = tid >> 6;
  const int l15 = lane & 15, q = lane >> 4;
  const int m0 = ob * 32;
  #pragma unroll
  for (int i = 0; i < 8; ++i) {
    int s = i * 512 + tid;                 // 32 rows x 128 chunks of 8 shorts
    int row = s >> 7, c = s & 127, cs = c ^ (row & 7);
    gl_lds_a(h2src + (size_t)(m0 + row) * K2q + Hd + cs * 8, sm + s * 8);
  }
  WAITVM(0);
  __syncthreads();
  if (w < 4) {
    const int ms = w & 1, nh = w >> 1;
    floatx4 acc[2] = {};
    const short* B0 = Wo + (nh * 32 + l15) * Hd;
    const int ra = ms * 16 + l15;
    for (int kk = 0; kk < Hd; kk += 32) {
      const int ch = (kk >> 3) + q;
      short8 a  = *(const short8*)(sm + (ra * 128 + (ch ^ (ra & 7))) * 8);
      short8 b0 = *(const short8*)(B0 + kk + q * 8);
      short8 b1 = *(const short8*)(B0 + 16 * Hd + kk + q * 8);
      acc[0] = MFMA16(a, b0, acc[0]);
      acc[1] = MFMA16(a, b1, acc[1]);
    }
    #pragma unroll
    for (int s2 = 0; s2 < 2; ++s2)
      #pragma unroll
      for (int r = 0; r < 4; ++r) {
        int m = m0 + ms * 16 + q * 4 + r;
        int n = nh * 32 + s2 * 16 + l15;
        float v = acc[s2][r] + bout[n];
        out[(size_t)m * (Sq * Od) + (size_t)tt * Od + n] = v;
        if (a1dst) st_wt(a1dst + (size_t)m * K1 + 1152 + n, f2bf(v));
      }
  }
  WAITVM(0);           // drain fp32 + write-through stores before publishing
  __syncthreads();
  if (ocnt && tid == 0)
    __hip_atomic_fetch_add(ocnt, 1, __ATOMIC_RELAXED, __HIP_MEMORY_SCOPE_AGENT);
  __syncthreads();     // protect sm before next step's stage
}

__global__ __launch_bounds__(512, 1) void lstm_main(Params p) {
  extern __shared__ __align__(16) short smem[];   // 3 x 40 KB = 120 KB
  const int tid = threadIdx.x;
  const int blk = blockIdx.x;

  if (blk < 128) {
    const int xcd = blk & 7, j = blk >> 3;        // 16 blocks per XCD
    const int bn = xcd * 2 + (j & 1);             // 0..15 (2 N-slices per XCD L2)
    const int m0 = (j >> 1) * 64;                 // mb 0..7
    const int lane = tid & 63, w = tid >> 6;
    const int l15 = lane & 15, q = lane >> 4;
    const int mh = w >> 2, gq = w & 3;
    const int colh = bn * 64 + gq * 16 + l15;

    float bA[4], bB[4], c1r[2][4], c2r[2][4];
    #pragma unroll
    for (int g = 0; g < 4; ++g) {
      bA[g] = p.b0v[g * Hd + colh];
      bB[g] = p.b1v[g * Hd + colh];
    }
    #pragma unroll
    for (int mt = 0; mt < 2; ++mt)
      #pragma unroll
      for (int r = 0; r < 4; ++r) {
        const int mg = m0 + mh * 32 + mt * 16 + q * 4 + r;
        c1r[mt][r] = p.c1[mg * Hd + colh];
        c2r[mt][r] = p.c2[mg * Hd + colh];
      }

    for (int t = 0; t < Sq; ++t) {
      const int par = t & 1;
      const short* A1p = par ? p.A1_1 : p.A1_0;
      short* A1n = par ? p.A1_0 : p.A1_1;
      short* A2p = par ? p.A2_1 : p.A2_0;
      short* A2n = par ? p.A2_0 : p.A2_1;
      // window A: layer-0 gates; A1 = [h1 | z | out(t-1)], out-chunk flag-guarded
      gemm_win(A1p, K1, 19, 16, p.W1r, bA, c1r,
               A1n, K1, 0, (short*)A2p, K2q, 0, m0, bn, smem, tid,
               p.outcnt, 16 * (t + 1));
      gbar(p.bcnt, p.bgen);
      // window B: layer-1 gates; h2n only into A2n
      gemm_win(A2p, K2q, 32, -2, p.W2r, bB, c2r,
               A2n, K2q, Hd, (short*)nullptr, 0, 0, m0, bn, smem, tid,
               nullptr, 0);
      gbar(p.bcnt, p.bgen);
    }
  } else {
    const int ob = blk - 128;   // 0..15
    for (int t = 0; t < Sq; ++t) {
      const int par = t & 1;
      const short* A2p = par ? p.A2_1 : p.A2_0;
      short* A1p = par ? p.A1_1 : p.A1_0;
      if (t > 0) {
        out_win(A2p, A1p, p.Woutb, p.bout, p.out, t - 1, ob, smem, tid, p.outcnt);
      } else {
        if (tid == 0)
          __hip_atomic_fetch_add(p.outcnt, 1, __ATOMIC_RELAXED, __HIP_MEMORY_SCOPE_AGENT);
        __syncthreads();
      }
      gbar(p.bcnt, p.bgen);
      gbar(p.bcnt, p.bgen);
    }
    // final: out(255) from h2(255) in A2_0 (phase B of t=255 wrote A2n = A2_0)
    out_win(p.A2_0, (short*)nullptr, p.Woutb, p.bout, p.out, Sq - 1, ob, smem, tid, nullptr);
  }
}

// ================= host =================
extern "C" void kernel_launch(void* const* d_in, const int* in_sizes, int n_in,
                              void* d_out, int out_size, void* d_ws, size_t ws_size,
                              hipStream_t stream) {
  const float* z    = (const float*)d_in[0];
  const float* Wh   = (const float*)d_in[1];
  const float* bh   = (const float*)d_in[2];
  const float* Wc   = (const float*)d_in[3];
  const float* bc   = (const float*)d_in[4];
  const float* Wih0 = (const float*)d_in[5];
  const float* Whh0 = (const float*)d_in[6];
  const float* bih0 = (const float*)d_in[7];
  const float* bhh0 = (const float*)d_in[8];
  const float* Wih1 = (const float*)d_in[9];
  const float* Whh1 = (const float*)d_in[10];
  const float* bih1 = (const float*)d_in[11];
  const float* bhh1 = (const float*)d_in[12];
  const float* Wout = (const float*)d_in[13];
  const float* bout = (const float*)d_in[14];
  float* out = (float*)d_out;

  char* ws = (char*)d_ws;
  size_t off = 0;
  auto carve = [&](size_t bytes) { char* p = ws + off; off = (off + bytes + 255) & ~size_t(255); return p; };
  short* W1r   = (short*)carve((size_t)G4H * K1 * 2);
  short* W2r   = (short*)carve((size_t)G4H * K2q * 2);
  short* Woutb = (short*)carve((size_t)Od * Hd * 2);
  float* b0v   = (float*)carve(G4H * 4);
  float* b1v   = (float*)carve(G4H * 4);
  short* A1_0  = (short*)carve((size_t)Bt * K1 * 2);
  short* A1_1  = (short*)carve((size_t)Bt * K1 * 2);
  short* A2_0  = (short*)carve((size_t)Bt * K2q * 2);
  short* A2_1  = (short*)carve((size_t)Bt * K2q * 2);
  float* c1    = (float*)carve((size_t)Bt * Hd * 4);
  float* c2    = (float*)carve((size_t)Bt * Hd * 4);
  int*   barr  = (int*)carve(256);   // [0]=cnt [1]=gen [2]=outcnt

  k_conv_w1a<<<16384, 256, 0, stream>>>(Whh0, W1r);
  k_conv_w1c<<<2048, 256, 0, stream>>>(Wih0, W1r);
  k_conv_w1d<<<1024, 256, 0, stream>>>(Wih0, W1r);
  k_conv_w2 <<<32768, 256, 0, stream>>>(Wih1, Whh1, W2r);
  k_conv_wout<<<256, 256, 0, stream>>>(Wout, Woutb);
  k_vec<<<16, 256, 0, stream>>>(bih0, bhh0, bih1, bhh1, b0v, b1v, barr);
  k_init<<<2048, 256, 0, stream>>>(z, Wh, bh, Wc, bc, A1_0, A2_0, c1, c2);
  k_initz<<<256, 256, 0, stream>>>(z, A1_0, A1_1);

  Params pr{W1r, W2r, Woutb, b0v, b1v, bout,
            A1_0, A1_1, A2_0, A2_1, c1, c2, out,
            (unsigned*)barr, (unsigned*)(barr + 1), barr + 2};

  (void)hipFuncSetAttribute((const void*)lstm_main,
                            hipFuncAttributeMaxDynamicSharedMemorySize, LDS_BYTES);
  lstm_main<<<dim3(NBLK), dim3(512), LDS_BYTES, stream>>>(pr);
}

// Round 5
// 12293.621 us; speedup vs baseline: 2.2185x; 1.1325x over previous
//
#include <hip/hip_runtime.h>

// Problem dims
#define Lz   128
#define Hd   1024
#define Od   64
#define Sq   256
#define Bt   512
#define K1   1216   // h1(1024) | z(128) | out(64)  -- fold un-materialized (rank-64)
#define K2q  2048   // h1n(1024) | h2(1024)
#define G4H  4096
#define NBLK 256u   // 8 XCD-teams x 32 blocks; team = batch-slice of 64 rows

typedef __attribute__((ext_vector_type(8))) short  short8;
typedef __attribute__((ext_vector_type(4))) float  floatx4;

__device__ __forceinline__ short f2bf(float x) {
  unsigned u = __float_as_uint(x);
  unsigned r = (u + 0x7fffu + ((u >> 16) & 1u)) >> 16;
  return (short)r;
}
__device__ __forceinline__ float sigf(float x)   { return 1.0f / (1.0f + __expf(-x)); }
__device__ __forceinline__ float tanhf_(float x) { return 1.0f - 2.0f / (__expf(2.0f * x) + 1.0f); }

// static data (z cols): full caching (L1+L2), reused every step
__device__ __forceinline__ void gl_lds_z(const short* g, void* l) {
  __builtin_amdgcn_global_load_lds(
      (__attribute__((address_space(1))) const void*)g,
      (__attribute__((address_space(3))) void*)l, 16, 0, 0);
}
// XCD-local activation load: sc0 only -> bypass (possibly stale) L1, hit the
// XCD's shared L2 where same-XCD producers' dirty lines live. No fabric trip.
__device__ __forceinline__ void gl_lds_a(const short* g, void* l) {
  __builtin_amdgcn_global_load_lds(
      (__attribute__((address_space(1))) const void*)g,
      (__attribute__((address_space(3))) void*)l, 16, 0, 1);
}
// weight stream: nt (no L2 allocate) -- each block owns a distinct gate slice,
// zero reuse within a step and 26.8MB/XCD/step can never stay in 4MB L2; nt
// keeps the W stream from evicting the XCD-local activation lines.
__device__ __forceinline__ void gl_lds_w(const short* g, void* l) {
  __builtin_amdgcn_global_load_lds(
      (__attribute__((address_space(1))) const void*)g,
      (__attribute__((address_space(3))) void*)l, 16, 0, 2);
}
// h-state store: sc0 (L1 write-through) -> lands in the XCD's shared L2 (dirty,
// write-back). Intra-XCD coherent; no MALL write-through needed any more.
__device__ __forceinline__ void st_wt(short* p, short v) {
  asm volatile("global_store_short %0, %1, off sc0"
               :: "v"(p), "v"((unsigned)(unsigned short)v) : "memory");
}

#define S_BARRIER() asm volatile("s_barrier" ::: "memory")
#define WAITVM(n)   asm volatile("s_waitcnt vmcnt(" #n ")" ::: "memory")

// ---- per-XCD barrier over the 32-block team (relaxed agent atomics, proven
// pattern). __syncthreads drains vmem (compiler emits waitcnt before barrier),
// so epilogue stores are in L2 before the counter bump.
__device__ __forceinline__ void xbar(int* b) {   // b: [cnt, gen]
  __syncthreads();
  if (threadIdx.x == 0) {
    unsigned* cnt = (unsigned*)b;
    unsigned* gen = (unsigned*)b + 1;
    unsigned g = __hip_atomic_load(gen, __ATOMIC_RELAXED, __HIP_MEMORY_SCOPE_AGENT);
    unsigned a = __hip_atomic_fetch_add(cnt, 1u, __ATOMIC_RELAXED, __HIP_MEMORY_SCOPE_AGENT);
    if (a == 31u) {
      __hip_atomic_store(cnt, 0u, __ATOMIC_RELAXED, __HIP_MEMORY_SCOPE_AGENT);
      __hip_atomic_store(gen, g + 1u, __ATOMIC_RELAXED, __HIP_MEMORY_SCOPE_AGENT);
    } else {
      while (__hip_atomic_load(gen, __ATOMIC_RELAXED, __HIP_MEMORY_SCOPE_AGENT) == g)
        __builtin_amdgcn_s_sleep(8);
    }
  }
  __syncthreads();
}

// ---- weight row reorder: group bn (0..63) holds 64 rows: gate g (ifgo), j (0..15)
__device__ __forceinline__ int oldrow(int nr) {
  int bn = nr >> 6, rem = nr & 63, g = rem >> 4, jj = rem & 15;
  return g * Hd + bn * 16 + jj;
}

struct Params {
  const short *W1r, *W2r, *Woutb;
  const float *b0v, *b1v, *bout;
  short *A1_0, *A1_1, *A2_0, *A2_1;
  float *c1, *c2, *out;
  int *barr;   // 8 x 16 ints: per-XCD [cnt, gen, outcnt, teamreg, pad...]
};

// ================= prep kernels =================
__global__ void k_conv_w1a(const float* __restrict__ Whh0, short* __restrict__ W1r) {
  int idx = blockIdx.x * 256 + threadIdx.x;        // 4096*1024
  int nr = idx >> 10, k = idx & 1023;
  W1r[nr * K1 + k] = f2bf(Whh0[oldrow(nr) * Hd + k]);
}
__global__ void k_conv_w1c(const float* __restrict__ Wih0, short* __restrict__ W1r) {
  int idx = blockIdx.x * 256 + threadIdx.x;        // 4096*128 (z cols)
  int nr = idx >> 7, kz = idx & 127;
  W1r[nr * K1 + 1024 + kz] = f2bf(Wih0[oldrow(nr) * (Lz + Od) + kz]);
}
__global__ void k_conv_w1d(const float* __restrict__ Wih0, short* __restrict__ W1r) {
  int idx = blockIdx.x * 256 + threadIdx.x;        // 4096*64 (out-feedback cols)
  int nr = idx >> 6, j = idx & 63;
  W1r[nr * K1 + 1152 + j] = f2bf(Wih0[oldrow(nr) * (Lz + Od) + Lz + j]);
}
__global__ void k_conv_w2(const float* __restrict__ Wih1, const float* __restrict__ Whh1,
                          short* __restrict__ W2r) {
  int idx = blockIdx.x * 256 + threadIdx.x;        // 4096*2048
  int nr = idx >> 11, k = idx & 2047;
  int orow = oldrow(nr);
  float v = (k < Hd) ? Wih1[orow * Hd + k] : Whh1[orow * Hd + (k - Hd)];
  W2r[nr * K2q + k] = f2bf(v);
}
__global__ void k_conv_wout(const float* __restrict__ Wout, short* __restrict__ Woutb) {
  int idx = blockIdx.x * 256 + threadIdx.x;        // 64*1024
  Woutb[idx] = f2bf(Wout[idx]);
}
__global__ void k_vec(const float* __restrict__ bih0, const float* __restrict__ bhh0,
                      const float* __restrict__ bih1, const float* __restrict__ bhh1,
                      float* __restrict__ b0v, float* __restrict__ b1v,
                      int* __restrict__ barzero) {
  int n = blockIdx.x * 256 + threadIdx.x;          // 4096 (original gate order)
  if (n < 256) barzero[n] = 0;                     // zero barrier/team/outcnt state
  b0v[n] = bih0[n] + bhh0[n];
  b1v[n] = bih1[n] + bhh1[n];
}
__global__ void k_init(const float* __restrict__ z, const float* __restrict__ Wh,
                       const float* __restrict__ bh, const float* __restrict__ Wc,
                       const float* __restrict__ bc,
                       short* __restrict__ A1_0, short* __restrict__ A2_0,
                       float* __restrict__ c1, float* __restrict__ c2) {
  int idx = blockIdx.x * 256 + threadIdx.x;        // 512*1024
  int m = idx >> 10, n = idx & 1023;
  const float* zr = z + m * Lz;
  const float* whr = Wh + n * Lz;
  const float* wcr = Wc + n * Lz;
  float hh = bh[n], cc = bc[n];
  #pragma unroll 8
  for (int k = 0; k < Lz; ++k) { float zv = zr[k]; hh += zv * whr[k]; cc += zv * wcr[k]; }
  c1[idx] = cc;
  c2[idx] = cc;
  short hb = f2bf(hh);
  A1_0[m * K1 + n] = hb;                 // h1(-1) = h0
  if (n < Od) A1_0[m * K1 + 1152 + n] = 0;   // out(-1) = 0
  A2_0[m * K2q + Hd + n] = hb;           // h2(-1) = h0
}
__global__ void k_initz(const float* __restrict__ z, short* __restrict__ A1_0,
                        short* __restrict__ A1_1) {
  int idx = blockIdx.x * 256 + threadIdx.x;        // 512*128
  int m = idx >> 7, k = idx & 127;
  short v = f2bf(z[idx]);
  A1_0[m * K1 + 1024 + k] = v;
  A1_1[m * K1 + 1024 + k] = v;
}

// ================= main persistent kernel =================
#define MFMA16(a, b, c) __builtin_amdgcn_mfma_f32_16x16x32_bf16(a, b, c, 0, 0, 0)
#define BUFSH 12288   // shorts per ring buffer: A 64x64 (4096) + W 128x64 (8192)
#define NBUF  4       // prefetch depth 3
#define LDS_BYTES (NBUF * BUFSH * 2)   // 96 KB -> forces exactly 1 block/CU

// ---- folded out-projection, register-based: 4 blocks/XCD (slots 0,8,16,24),
// 16 batch rows each. h2 rows read from the XCD's L2 (sc0); Wout cached.
// Exact-count vmcnt pipelining, 2 groups deep. (R2-verified compute core.)
__device__ __forceinline__ void out_reg(const short* __restrict__ h2src,
    const short* __restrict__ Wo, const float* __restrict__ boutv,
    float* __restrict__ outp, int tt, int mo,
    short* __restrict__ ofb, int tid, int* __restrict__ ocnt)
{
  const int lane = tid & 63, w = tid >> 6;
  const int l15 = lane & 15, q = lane >> 4;
  const short* ap = h2src + (size_t)(mo + l15) * K2q + Hd + q * 8;
  const short* bp = Wo + (size_t)(w * 16 + l15) * Hd + q * 8;
  floatx4 acc = {};
  short8 A0, B0, A1, B1, A2, B2, A3, B3;
#define OLA(r, kk) asm volatile("global_load_dwordx4 %0, %1, off sc0" \
    : "=v"(r) : "v"(ap + (kk) * 32) : "memory")
#define OLB(r, kk) asm volatile("global_load_dwordx4 %0, %1, off" \
    : "=v"(r) : "v"(bp + (kk) * 32) : "memory")
  OLA(A0, 0); OLB(B0, 0); OLA(A1, 1); OLB(B1, 1);     // group 0 (kk 0,1)
  OLA(A2, 2); OLB(B2, 2); OLA(A3, 3); OLB(B3, 3);     // group 1 (kk 2,3)
  #pragma unroll
  for (int g = 0; g < 16; g += 2) {
    WAITVM(4); __builtin_amdgcn_sched_barrier(0);      // group g retired
    acc = MFMA16(A0, B0, acc); acc = MFMA16(A1, B1, acc);
    if (g + 2 < 16) { OLA(A0, 2*(g+2)); OLB(B0, 2*(g+2));
                      OLA(A1, 2*(g+2)+1); OLB(B1, 2*(g+2)+1); }
    if (g + 3 < 16) { WAITVM(4); } else { WAITVM(0); } // group g+1 retired
    __builtin_amdgcn_sched_barrier(0);
    acc = MFMA16(A2, B2, acc); acc = MFMA16(A3, B3, acc);
    if (g + 3 < 16) { OLA(A2, 2*(g+3)); OLB(B2, 2*(g+3));
                      OLA(A3, 2*(g+3)+1); OLB(B3, 2*(g+3)+1); }
  }
#undef OLA
#undef OLB
  #pragma unroll
  for (int r = 0; r < 4; ++r) {
    int m = mo + q * 4 + r;
    int n = w * 16 + l15;
    float v = acc[r] + boutv[n];
    outp[(size_t)m * (Sq * Od) + (size_t)tt * Od + n] = v;
    if (ofb) st_wt(ofb + (size_t)m * K1 + 1152 + n, f2bf(v));
  }
  WAITVM(0);          // each wave drains its own feedback stores
  __syncthreads();    // all waves' stores in L2 before publishing
  if (ocnt && tid == 0)
    __hip_atomic_fetch_add(ocnt, 1, __ATOMIC_RELAXED, __HIP_MEMORY_SCOPE_AGENT);
}

// 64x128 tile, 4 waves (R0-proven core): w = mh*2+gh. XOR-swizzled LDS:
// chunk-slot sl of row r holds global chunk sl^(r&7). Ring NBUF=4, depth 3.
__device__ __forceinline__ void gemm_win(
    const short* __restrict__ Asrc, int astride, int nk, int zstart,
    const short* __restrict__ Wsrc,
    const float* __restrict__ bz, float cr[2][4],
    short* __restrict__ hd0, int hs0, int ho0,
    short* __restrict__ hd1, int hs1, int ho1,
    int m0, int bn2, short* sm, int tid,
    int* __restrict__ ocnt, int othresh)
{
  const int lane = tid & 63, w = tid >> 6;
  const int l15 = lane & 15, q = lane >> 4;
  const int mh = w >> 1, gh = w & 1;
  floatx4 acc[2][4] = {};

  const short* Ab = Asrc + (size_t)m0 * astride;
  const short* Wb = Wsrc + (size_t)(bn2 * 128) * astride;

  auto stage = [&](int kk, int b) {
    const int kb = kk * 64;
    short* as = sm + b * BUFSH;
    short* ws = as + 4096;
    const bool stat = (kk == zstart) || (kk == zstart + 1);   // static z cols
    #pragma unroll
    for (int i = 0; i < 2; ++i) {
      int s = i * 256 + tid;
      int row = s >> 3, cg = (s & 7) ^ (row & 7);
      const short* gp = Ab + (size_t)row * astride + kb + cg * 8;
      if (stat) gl_lds_z(gp, as + s * 8);
      else      gl_lds_a(gp, as + s * 8);
    }
    #pragma unroll
    for (int i = 0; i < 4; ++i) {
      int s = i * 256 + tid;
      int row = s >> 3, cg = (s & 7) ^ (row & 7);
      gl_lds_w(Wb + (size_t)row * astride + kb + cg * 8, ws + s * 8);
    }
  };

  stage(0, 0);
  stage(1, 1);
  stage(2, 2);
  for (int kk = 0; kk < nk; ++kk) {
    S_BARRIER();
    if (kk + 3 < nk) {
      if (ocnt && kk + 3 == nk - 1) {     // out-feedback chunk: wait for out-jobs
        while (__hip_atomic_load(ocnt, __ATOMIC_RELAXED, __HIP_MEMORY_SCOPE_AGENT) < othresh)
          __builtin_amdgcn_s_sleep(1);
      }
      stage(kk + 3, (kk + 3) & 3);
      WAITVM(18);
    }
    else if (kk + 2 < nk) { WAITVM(12); }
    else if (kk + 1 < nk) { WAITVM(6); }
    else { WAITVM(0); }
    S_BARRIER();
    const short* as = sm + (kk & 3) * BUFSH;
    const short* ws = as + 4096;
    #pragma unroll
    for (int ks = 0; ks < 2; ++ks) {
      const int cc = ks * 4 + q;
      short8 a[2];
      #pragma unroll
      for (int mt = 0; mt < 2; ++mt) {
        const int ra = mh * 32 + mt * 16 + l15;
        a[mt] = *(const short8*)(as + (ra * 8 + (cc ^ (ra & 7))) * 8);
      }
      #pragma unroll
      for (int g = 0; g < 4; ++g) {
        const int rw = gh * 64 + g * 16 + l15;
        short8 b = *(const short8*)(ws + (rw * 8 + (cc ^ (rw & 7))) * 8);
        acc[0][g] = MFMA16(a[0], b, acc[0][g]);
        acc[1][g] = MFMA16(a[1], b, acc[1][g]);
      }
    }
  }
  // fused LSTM cell epilogue; h stored to the XCD-shared L2 (sc0)
  #pragma unroll
  for (int mt = 0; mt < 2; ++mt) {
    #pragma unroll
    for (int r = 0; r < 4; ++r) {
      const int mg = m0 + mh * 32 + mt * 16 + q * 4 + r;
      const int colh = bn2 * 32 + gh * 16 + l15;
      float iv = acc[mt][0][r] + bz[0];
      float fv = acc[mt][1][r] + bz[1];
      float gv = acc[mt][2][r] + bz[2];
      float ov = acc[mt][3][r] + bz[3];
      float cn = sigf(fv) * cr[mt][r] + sigf(iv) * tanhf_(gv);
      cr[mt][r] = cn;
      short hb = f2bf(sigf(ov) * tanhf_(cn));
      st_wt(hd0 + (size_t)mg * hs0 + ho0 + colh, hb);
      if (hd1) st_wt(hd1 + (size_t)mg * hs1 + ho1 + colh, hb);
    }
  }
}

__global__ __launch_bounds__(256, 1) void lstm_main(Params p) {
  extern __shared__ __align__(16) short smem[];   // 4 x 24 KB = 96 KB
  const int tid = threadIdx.x;

  // ---- dynamic XCD-team formation: correctness does NOT depend on the
  // blockIdx->XCD mapping. Each block joins the team of the XCD it actually
  // runs on; 96KB LDS guarantees 1 block/CU -> exactly 32 blocks per XCD.
  __shared__ int sh_ids[2];
  if (tid == 0) {
    unsigned xr;
    asm volatile("s_getreg_b32 %0, hwreg(HW_REG_XCC_ID)" : "=s"(xr));
    int xcc = (int)(xr & 7u);
    int slot = (int)__hip_atomic_fetch_add((unsigned*)(p.barr + xcc * 16 + 3), 1u,
                                           __ATOMIC_RELAXED, __HIP_MEMORY_SCOPE_AGENT);
    sh_ids[0] = xcc;
    sh_ids[1] = slot & 31;
  }
  __syncthreads();
  const int xcc  = sh_ids[0];
  const int slot = sh_ids[1];
  int* xb = p.barr + xcc * 16;          // [0]=cnt [1]=gen [2]=outcnt

  const int m0 = xcc * 64;              // this XCD's batch slice (64 rows)
  const int bn2 = slot;                 // gate-col slice: h-cols [slot*32, +32)
  const bool ojob = ((slot & 7) == 0);  // 4 out-jobs per XCD
  const int mo = xcc * 64 + (slot >> 3) * 16;   // out-job batch rows (16 each)

  const int lane = tid & 63, w = tid >> 6;
  const int l15 = lane & 15, q = lane >> 4;
  const int mh = w >> 1, gh = w & 1;
  const int colh = bn2 * 32 + gh * 16 + l15;

  float bA[4], bB[4], c1r[2][4], c2r[2][4];
  #pragma unroll
  for (int g = 0; g < 4; ++g) {
    bA[g] = p.b0v[g * Hd + colh];
    bB[g] = p.b1v[g * Hd + colh];
  }
  #pragma unroll
  for (int mt = 0; mt < 2; ++mt)
    #pragma unroll
    for (int r = 0; r < 4; ++r) {
      const int mg = m0 + mh * 32 + mt * 16 + q * 4 + r;
      c1r[mt][r] = p.c1[mg * Hd + colh];
      c2r[mt][r] = p.c2[mg * Hd + colh];
    }

  for (int t = 0; t < Sq; ++t) {
    const int par = t & 1;
    const short* A1p = par ? p.A1_1 : p.A1_0;
    short* A1n = par ? p.A1_0 : p.A1_1;
    short* A2p = par ? p.A2_1 : p.A2_0;
    short* A2n = par ? p.A2_0 : p.A2_1;
    // out(t-1) on designated blocks (reads h2(t-1) from this XCD's L2, writes
    // feedback into A1p out-segment + bumps outcnt). Other blocks proceed into
    // window A and only wait at the out-feedback chunk.
    if (ojob && t > 0)
      out_reg(A2p, p.Woutb, p.bout, p.out, t - 1, mo, (short*)A1p, tid, xb + 2);
    // window A: layer-0 gates; A1 = [h1 | z | out(t-1)], out-chunk flag-guarded
    gemm_win(A1p, K1, 19, 16, p.W1r, bA, c1r,
             A1n, K1, 0, (short*)A2p, K2q, 0, m0, bn2, smem, tid,
             xb + 2, 4 * t);
    xbar(xb);
    // window B: layer-1 gates; h2n only into A2n
    gemm_win(A2p, K2q, 32, -2, p.W2r, bB, c2r,
             A2n, K2q, Hd, (short*)nullptr, 0, 0, m0, bn2, smem, tid,
             nullptr, 0);
    xbar(xb);
  }
  // final: out(255) from h2(255) in A2_0 (phase B of t=255 wrote A2n = A2_0)
  if (ojob)
    out_reg(p.A2_0, p.Woutb, p.bout, p.out, Sq - 1, mo, (short*)nullptr, tid, nullptr);
}

// ================= host =================
extern "C" void kernel_launch(void* const* d_in, const int* in_sizes, int n_in,
                              void* d_out, int out_size, void* d_ws, size_t ws_size,
                              hipStream_t stream) {
  const float* z    = (const float*)d_in[0];
  const float* Wh   = (const float*)d_in[1];
  const float* bh   = (const float*)d_in[2];
  const float* Wc   = (const float*)d_in[3];
  const float* bc   = (const float*)d_in[4];
  const float* Wih0 = (const float*)d_in[5];
  const float* Whh0 = (const float*)d_in[6];
  const float* bih0 = (const float*)d_in[7];
  const float* bhh0 = (const float*)d_in[8];
  const float* Wih1 = (const float*)d_in[9];
  const float* Whh1 = (const float*)d_in[10];
  const float* bih1 = (const float*)d_in[11];
  const float* bhh1 = (const float*)d_in[12];
  const float* Wout = (const float*)d_in[13];
  const float* bout = (const float*)d_in[14];
  float* out = (float*)d_out;

  char* ws = (char*)d_ws;
  size_t off = 0;
  auto carve = [&](size_t bytes) { char* p = ws + off; off = (off + bytes + 255) & ~size_t(255); return p; };
  short* W1r   = (short*)carve((size_t)G4H * K1 * 2);
  short* W2r   = (short*)carve((size_t)G4H * K2q * 2);
  short* Woutb = (short*)carve((size_t)Od * Hd * 2);
  float* b0v   = (float*)carve(G4H * 4);
  float* b1v   = (float*)carve(G4H * 4);
  short* A1_0  = (short*)carve((size_t)Bt * K1 * 2);
  short* A1_1  = (short*)carve((size_t)Bt * K1 * 2);
  short* A2_0  = (short*)carve((size_t)Bt * K2q * 2);
  short* A2_1  = (short*)carve((size_t)Bt * K2q * 2);
  float* c1    = (float*)carve((size_t)Bt * Hd * 4);
  float* c2    = (float*)carve((size_t)Bt * Hd * 4);
  int*   barr  = (int*)carve(1024);  // 8 XCDs x 16 ints: [cnt,gen,outcnt,team,...]

  k_conv_w1a<<<16384, 256, 0, stream>>>(Whh0, W1r);
  k_conv_w1c<<<2048, 256, 0, stream>>>(Wih0, W1r);
  k_conv_w1d<<<1024, 256, 0, stream>>>(Wih0, W1r);
  k_conv_w2 <<<32768, 256, 0, stream>>>(Wih1, Whh1, W2r);
  k_conv_wout<<<256, 256, 0, stream>>>(Wout, Woutb);
  k_vec<<<16, 256, 0, stream>>>(bih0, bhh0, bih1, bhh1, b0v, b1v, barr);
  k_init<<<2048, 256, 0, stream>>>(z, Wh, bh, Wc, bc, A1_0, A2_0, c1, c2);
  k_initz<<<256, 256, 0, stream>>>(z, A1_0, A1_1);

  Params pr{W1r, W2r, Woutb, b0v, b1v, bout,
            A1_0, A1_1, A2_0, A2_1, c1, c2, out, barr};

  (void)hipFuncSetAttribute((const void*)lstm_main,
                            hipFuncAttributeMaxDynamicSharedMemorySize, LDS_BYTES);
  lstm_main<<<dim3(NBLK), dim3(256), LDS_BYTES, stream>>>(pr);
}